// Round 3
// baseline (175.354 us; speedup 1.0000x reference)
//
#include <hip/hip_runtime.h>
#include <math.h>

#define TEMP_INV 20.0f
#define EPS_F 1e-6f

// Fused: per-row cosine sim vs anchor, exp(), block partials, and the last
// block (device-scope ticket) reduces partials + computes the final loss.
__global__ __launch_bounds__(256) void infonce_fused(
    const float* __restrict__ a,
    const float* __restrict__ p,
    const float* __restrict__ neg,
    float* __restrict__ partials,
    unsigned* __restrict__ counter,
    float* __restrict__ out,
    int N)
{
    __shared__ float a_lds[1024];
    __shared__ float red[256];
    __shared__ int s_last;

    const int tid = threadIdx.x;

    // Stage anchor into LDS and compute ||a||^2 cooperatively (per block).
    float4 av = ((const float4*)a)[tid];
    ((float4*)a_lds)[tid] = av;
    red[tid] = av.x * av.x + av.y * av.y + av.z * av.z + av.w * av.w;
    __syncthreads();
    for (int s = 128; s > 0; s >>= 1) {
        if (tid < s) red[tid] += red[tid + s];
        __syncthreads();
    }
    const float anorm = sqrtf(red[0]);
    __syncthreads();  // red reused below

    const int lane = tid & 63;
    const int wave = tid >> 6;

    // Lane's anchor fragment, interleaved: float4 index j*64 + lane.
    float4 areg[4];
    #pragma unroll
    for (int j = 0; j < 4; ++j)
        areg[j] = ((const float4*)a_lds)[j * 64 + lane];

    const int gwave = blockIdx.x * 4 + wave;
    const int total_waves = gridDim.x * 4;
    const int chunk = (N + total_waves - 1) / total_waves;
    const int base = gwave * chunk;
    const int end = (base + chunk < N) ? base + chunk : N;

    float local = 0.0f;
    for (int row = base; row < end; row += 2) {
        const bool two = (row + 1 < end);  // wave-uniform
        const float4* r0 = (const float4*)neg + (size_t)row * 256;
        const float4* r1 = r0 + 256;

        float4 v0[4], v1[4];
        #pragma unroll
        for (int j = 0; j < 4; ++j) v0[j] = r0[j * 64 + lane];
        if (two) {
            #pragma unroll
            for (int j = 0; j < 4; ++j) v1[j] = r1[j * 64 + lane];
        }

        float d0 = 0.f, n0 = 0.f, d1 = 0.f, n1 = 0.f;
        #pragma unroll
        for (int j = 0; j < 4; ++j) {
            d0 += v0[j].x * areg[j].x + v0[j].y * areg[j].y
                + v0[j].z * areg[j].z + v0[j].w * areg[j].w;
            n0 += v0[j].x * v0[j].x + v0[j].y * v0[j].y
                + v0[j].z * v0[j].z + v0[j].w * v0[j].w;
        }
        if (two) {
            #pragma unroll
            for (int j = 0; j < 4; ++j) {
                d1 += v1[j].x * areg[j].x + v1[j].y * areg[j].y
                    + v1[j].z * areg[j].z + v1[j].w * areg[j].w;
                n1 += v1[j].x * v1[j].x + v1[j].y * v1[j].y
                    + v1[j].z * v1[j].z + v1[j].w * v1[j].w;
            }
        }

        #pragma unroll
        for (int off = 32; off > 0; off >>= 1) {
            d0 += __shfl_xor(d0, off);
            n0 += __shfl_xor(n0, off);
            d1 += __shfl_xor(d1, off);
            n1 += __shfl_xor(n1, off);
        }

        const float s0 = d0 / fmaxf(anorm * sqrtf(n0), EPS_F) * TEMP_INV;
        local += expf(s0);
        if (two) {
            const float s1 = d1 / fmaxf(anorm * sqrtf(n1), EPS_F) * TEMP_INV;
            local += expf(s1);
        }
    }

    if (lane == 0) red[wave] = local;
    __syncthreads();

    // Publish block partial (device-scope), draw a ticket.
    if (tid == 0) {
        const float blocksum = red[0] + red[1] + red[2] + red[3];
        __hip_atomic_store(&partials[blockIdx.x], blocksum,
                           __ATOMIC_RELAXED, __HIP_MEMORY_SCOPE_AGENT);
        __threadfence();
        const unsigned t = __hip_atomic_fetch_add(
            counter, 1u, __ATOMIC_ACQ_REL, __HIP_MEMORY_SCOPE_AGENT);
        s_last = (t == gridDim.x - 1);
    }
    __syncthreads();

    if (s_last) {
        __threadfence();
        // a is still in LDS; load p and the partials, reduce, finish.
        float4 pv  = ((const float4*)p)[tid];
        float4 av2 = ((const float4*)a_lds)[tid];
        float dp = av2.x * pv.x + av2.y * pv.y + av2.z * pv.z + av2.w * pv.w;
        float pp = pv.x * pv.x + pv.y * pv.y + pv.z * pv.z + pv.w * pv.w;
        float ns = 0.0f;
        const int nb = gridDim.x;
        for (int i = tid; i < nb; i += 256)
            ns += __hip_atomic_load(&partials[i],
                                    __ATOMIC_RELAXED, __HIP_MEMORY_SCOPE_AGENT);
        __syncthreads();  // done reading a_lds; reuse as reduction space
        float* s_dp = a_lds;
        float* s_pp = a_lds + 256;
        float* s_ns = a_lds + 512;
        s_dp[tid] = dp; s_pp[tid] = pp; s_ns[tid] = ns;
        __syncthreads();
        for (int s = 128; s > 0; s >>= 1) {
            if (tid < s) {
                s_dp[tid] += s_dp[tid + s];
                s_pp[tid] += s_pp[tid + s];
                s_ns[tid] += s_ns[tid + s];
            }
            __syncthreads();
        }
        if (tid == 0) {
            const float pos_sim =
                s_dp[0] / fmaxf(anorm * sqrtf(s_pp[0]), EPS_F) * TEMP_INV;
            out[0] = -logf(expf(pos_sim) / s_ns[0] + EPS_F);
        }
    }
}

extern "C" void kernel_launch(void* const* d_in, const int* in_sizes, int n_in,
                              void* d_out, int out_size, void* d_ws, size_t ws_size,
                              hipStream_t stream) {
    const float* a   = (const float*)d_in[0];
    const float* p   = (const float*)d_in[1];
    const float* neg = (const float*)d_in[2];
    const int D = in_sizes[0];            // 1024 for this problem
    const int N = in_sizes[2] / D;        // 65536
    float* out       = (float*)d_out;
    float* partials  = (float*)d_ws;                    // nblocks floats
    unsigned* counter = (unsigned*)((char*)d_ws + 8192); // after partials

    int nblocks = 2048;                   // 8 blocks/CU, 32 waves/CU resident
    if (nblocks * 4 > N) nblocks = (N + 3) / 4;

    hipMemsetAsync(counter, 0, sizeof(unsigned), stream);
    infonce_fused<<<nblocks, 256, 0, stream>>>(a, p, neg, partials, counter,
                                               out, N);
}

// Round 4
// 48.499 us; speedup vs baseline: 3.6156x; 3.6156x over previous
//
#include <hip/hip_runtime.h>
#include <math.h>

#define TEMP_INV 20.0f
#define EPS_F 1e-6f

// Kernel 1: per-row cosine sim vs anchor, exp(), per-block partial sums.
// Wave-local prologue (no barriers), software-pipelined main loop:
// next row-pair's 8 float4 loads are issued BEFORE the current pair's
// shfl-reduce chain, so loads stay in flight during the dependent phase.
__global__ __launch_bounds__(256) void infonce_neg_pass(
    const float* __restrict__ a,
    const float* __restrict__ neg,
    float* __restrict__ partials,
    int N)
{
    __shared__ float red[4];

    const int tid = threadIdx.x;
    const int lane = tid & 63;
    const int wave = tid >> 6;

    // Anchor fragment straight from global (4 KB, L2-resident after first
    // touch). No LDS, no barriers.
    float4 areg[4];
    #pragma unroll
    for (int j = 0; j < 4; ++j)
        areg[j] = ((const float4*)a)[j * 64 + lane];

    float an = 0.0f;
    #pragma unroll
    for (int j = 0; j < 4; ++j)
        an += areg[j].x * areg[j].x + areg[j].y * areg[j].y
            + areg[j].z * areg[j].z + areg[j].w * areg[j].w;
    #pragma unroll
    for (int off = 32; off > 0; off >>= 1)
        an += __shfl_xor(an, off);
    const float anorm = sqrtf(an);

    const int gwave = blockIdx.x * 4 + wave;
    const int total_waves = gridDim.x * 4;
    const int chunk = (N + total_waves - 1) / total_waves;
    const int base = gwave * chunk;
    const int end = (base + chunk < N) ? base + chunk : N;

    float local = 0.0f;

    // Software pipeline: cur pair in {c0,c1}, next pair prefetched to {n0x,n1x}.
    float4 c0[4], c1[4], n0x[4], n1x[4];
    {
        const bool have = base < end;
        const bool two = base + 1 < end;
        const float4* r0 = (const float4*)neg + (size_t)base * 256;
        if (have) {
            #pragma unroll
            for (int j = 0; j < 4; ++j) c0[j] = r0[j * 64 + lane];
        }
        if (two) {
            #pragma unroll
            for (int j = 0; j < 4; ++j) c1[j] = r0[256 + j * 64 + lane];
        }
    }

    for (int row = base; row < end; row += 2) {
        const bool ctwo = (row + 1 < end);      // current pair has 2 rows
        const int nrow = row + 2;
        const bool nhave = nrow < end;
        const bool ntwo = nrow + 1 < end;

        // Prefetch next pair FIRST — these stay in flight across the reduce.
        const float4* rn = (const float4*)neg + (size_t)nrow * 256;
        if (nhave) {
            #pragma unroll
            for (int j = 0; j < 4; ++j) n0x[j] = rn[j * 64 + lane];
        }
        if (ntwo) {
            #pragma unroll
            for (int j = 0; j < 4; ++j) n1x[j] = rn[256 + j * 64 + lane];
        }

        // Current pair: dot + norm accumulate.
        float d0 = 0.f, n0 = 0.f, d1 = 0.f, n1 = 0.f;
        #pragma unroll
        for (int j = 0; j < 4; ++j) {
            d0 += c0[j].x * areg[j].x + c0[j].y * areg[j].y
                + c0[j].z * areg[j].z + c0[j].w * areg[j].w;
            n0 += c0[j].x * c0[j].x + c0[j].y * c0[j].y
                + c0[j].z * c0[j].z + c0[j].w * c0[j].w;
        }
        if (ctwo) {
            #pragma unroll
            for (int j = 0; j < 4; ++j) {
                d1 += c1[j].x * areg[j].x + c1[j].y * areg[j].y
                    + c1[j].z * areg[j].z + c1[j].w * areg[j].w;
                n1 += c1[j].x * c1[j].x + c1[j].y * c1[j].y
                    + c1[j].z * c1[j].z + c1[j].w * c1[j].w;
            }
        }

        // Interleaved butterflies (the latency the prefetch hides).
        #pragma unroll
        for (int off = 32; off > 0; off >>= 1) {
            d0 += __shfl_xor(d0, off);
            n0 += __shfl_xor(n0, off);
            d1 += __shfl_xor(d1, off);
            n1 += __shfl_xor(n1, off);
        }

        const float s0 = d0 / fmaxf(anorm * sqrtf(n0), EPS_F) * TEMP_INV;
        local += expf(s0);
        if (ctwo) {
            const float s1 = d1 / fmaxf(anorm * sqrtf(n1), EPS_F) * TEMP_INV;
            local += expf(s1);
        }

        // Advance pipeline (register renaming removes the copies).
        #pragma unroll
        for (int j = 0; j < 4; ++j) { c0[j] = n0x[j]; c1[j] = n1x[j]; }
    }

    if (lane == 0) red[wave] = local;
    __syncthreads();
    if (tid == 0)
        partials[blockIdx.x] = red[0] + red[1] + red[2] + red[3];
}

// Kernel 2: single block. Reduce block partials, compute pos_sim, final loss.
__global__ __launch_bounds__(256) void infonce_finalize(
    const float* __restrict__ a,
    const float* __restrict__ p,
    const float* __restrict__ partials,
    int nparts,
    float* __restrict__ out)
{
    __shared__ float r0[256], r1[256], r2[256], r3[256];
    const int tid = threadIdx.x;

    float4 av = ((const float4*)a)[tid];
    float4 pv = ((const float4*)p)[tid];
    r0[tid] = av.x * pv.x + av.y * pv.y + av.z * pv.z + av.w * pv.w;
    r1[tid] = av.x * av.x + av.y * av.y + av.z * av.z + av.w * av.w;
    r2[tid] = pv.x * pv.x + pv.y * pv.y + pv.z * pv.z + pv.w * pv.w;

    float nloc = 0.0f;
    for (int i = tid; i < nparts; i += 256) nloc += partials[i];
    r3[tid] = nloc;
    __syncthreads();

    for (int s = 128; s > 0; s >>= 1) {
        if (tid < s) {
            r0[tid] += r0[tid + s];
            r1[tid] += r1[tid + s];
            r2[tid] += r2[tid + s];
            r3[tid] += r3[tid + s];
        }
        __syncthreads();
    }

    if (tid == 0) {
        const float pos_sim =
            r0[0] / fmaxf(sqrtf(r1[0]) * sqrtf(r2[0]), EPS_F) * TEMP_INV;
        out[0] = -logf(expf(pos_sim) / r3[0] + EPS_F);
    }
}

extern "C" void kernel_launch(void* const* d_in, const int* in_sizes, int n_in,
                              void* d_out, int out_size, void* d_ws, size_t ws_size,
                              hipStream_t stream) {
    const float* a   = (const float*)d_in[0];
    const float* p   = (const float*)d_in[1];
    const float* neg = (const float*)d_in[2];
    const int D = in_sizes[0];            // 1024 for this problem
    const int N = in_sizes[2] / D;        // 65536
    float* out      = (float*)d_out;
    float* partials = (float*)d_ws;       // nblocks floats

    int nblocks = 2048;                   // 8 blocks/CU
    if (nblocks * 4 > N) nblocks = (N + 3) / 4;

    infonce_neg_pass<<<nblocks, 256, 0, stream>>>(a, neg, partials, N);
    infonce_finalize<<<1, 256, 0, stream>>>(a, p, partials, nblocks, out);
}